// Round 1
// baseline (238.318 us; speedup 1.0000x reference)
//
#include <hip/hip_runtime.h>
#include <hip/hip_bf16.h>

typedef __attribute__((ext_vector_type(4))) float f32x4;
typedef __attribute__((ext_vector_type(8))) short bf16x8;

// Problem constants (B=2, S=2048, D=1024, H=16, DK=64)
#define Bn 2
#define Sn 2048
#define Dn 1024
#define Hn 16
#define DKn 64
#define Mrows (Bn * Sn)   // 4096

__device__ __forceinline__ unsigned short f2bf(float f) {
  unsigned int x = __float_as_uint(f);
  x += 0x7fffu + ((x >> 16) & 1u);   // round-to-nearest-even
  return (unsigned short)(x >> 16);
}

__device__ __forceinline__ f32x4 mfma16(bf16x8 a, bf16x8 b, f32x4 c) {
  return __builtin_amdgcn_mfma_f32_16x16x32_bf16(a, b, c, 0, 0, 0);
}

__device__ __forceinline__ void gload_lds16(const unsigned short* g, unsigned short* l) {
  __builtin_amdgcn_global_load_lds(
      (const __attribute__((address_space(1))) void*)g,
      (__attribute__((address_space(3))) void*)l, 16, 0, 0);
}

// ---------------------------------------------------------------------------
// fp32 -> bf16 convert (memory-bound, vectorized)
// ---------------------------------------------------------------------------
__global__ __launch_bounds__(256)
void cvt_f32_bf16(const float* __restrict__ in, unsigned short* __restrict__ out, int n) {
  int i = (blockIdx.x * 256 + threadIdx.x) * 4;
  if (i >= n) return;
  float4 v = *(const float4*)(in + i);
  ushort4 o;
  o.x = f2bf(v.x); o.y = f2bf(v.y); o.z = f2bf(v.z); o.w = f2bf(v.w);
  *(ushort4*)(out + i) = o;
}

// ---------------------------------------------------------------------------
// GEMM: C[M,N] = A[M,K] * W[N,K]^T  (bf16 in, fp32 accum, bf16 or fp32 out)
// M=4096, N=1024, K=1024.  128x128 tile, BK=64, 4 waves, m97 structure.
// ---------------------------------------------------------------------------
template<bool OUTF32>
__device__ __forceinline__ void gemm_body(const unsigned short* __restrict__ A,
                                          const unsigned short* __restrict__ W,
                                          unsigned short* __restrict__ Cb,
                                          float* __restrict__ Cf) {
  const int K = Dn, N = Dn;
  __shared__ unsigned short As[128 * 64];
  __shared__ unsigned short Bs[128 * 64];
  const int tid  = threadIdx.x;
  const int wid  = tid >> 6;
  const int lane = tid & 63;
  const int l15  = lane & 15;
  const int lg   = lane >> 4;
  const int row0 = blockIdx.x * 128;
  const int col0 = blockIdx.y * 128;
  const int wr = (wid >> 1) * 64;
  const int wc = (wid & 1) * 64;

  f32x4 acc[4][4] = {};

  const int srow = lane >> 3;          // 0..7 within a 1KB chunk
  const int scol = (lane & 7) * 8;     // element col, 16B granules

  for (int kt = 0; kt < K; kt += 64) {
#pragma unroll
    for (int p = 0; p < 4; ++p) {
      int chunk = p * 4 + wid;                       // 0..15
      int r = chunk * 8 + srow;
      gload_lds16(A + (size_t)(row0 + r) * K + kt + scol, &As[chunk * 512]);
    }
#pragma unroll
    for (int p = 0; p < 4; ++p) {
      int chunk = p * 4 + wid;
      int r = chunk * 8 + srow;
      gload_lds16(W + (size_t)(col0 + r) * K + kt + scol, &Bs[chunk * 512]);
    }
    __syncthreads();

#pragma unroll
    for (int kk = 0; kk < 2; ++kk) {
      bf16x8 af[4], bfr[4];
#pragma unroll
      for (int m = 0; m < 4; ++m)
        af[m] = *(const bf16x8*)(&As[(wr + m * 16 + l15) * 64 + kk * 32 + lg * 8]);
#pragma unroll
      for (int n = 0; n < 4; ++n)
        bfr[n] = *(const bf16x8*)(&Bs[(wc + n * 16 + l15) * 64 + kk * 32 + lg * 8]);
#pragma unroll
      for (int m = 0; m < 4; ++m)
#pragma unroll
        for (int n = 0; n < 4; ++n)
          acc[m][n] = mfma16(af[m], bfr[n], acc[m][n]);
    }
    __syncthreads();
  }

  // Epilogue: C/D layout col = lane&15, row = (lane>>4)*4 + j  [m89 verified]
#pragma unroll
  for (int m = 0; m < 4; ++m)
#pragma unroll
    for (int n = 0; n < 4; ++n) {
      int r0 = row0 + wr + m * 16 + lg * 4;
      int c  = col0 + wc + n * 16 + l15;
#pragma unroll
      for (int j = 0; j < 4; ++j) {
        size_t idx = (size_t)(r0 + j) * N + c;
        if (OUTF32) Cf[idx] = acc[m][n][j];
        else        Cb[idx] = f2bf(acc[m][n][j]);
      }
    }
}

__global__ __launch_bounds__(256)
void gemm_qkv(const unsigned short* __restrict__ A,
              const unsigned short* __restrict__ W0,
              const unsigned short* __restrict__ W1,
              const unsigned short* __restrict__ W2,
              unsigned short* __restrict__ C0,
              unsigned short* __restrict__ C1,
              unsigned short* __restrict__ C2) {
  const unsigned short* W = (blockIdx.z == 0) ? W0 : ((blockIdx.z == 1) ? W1 : W2);
  unsigned short* C       = (blockIdx.z == 0) ? C0 : ((blockIdx.z == 1) ? C1 : C2);
  gemm_body<false>(A, W, C, nullptr);
}

__global__ __launch_bounds__(256)
void gemm_out(const unsigned short* __restrict__ A,
              const unsigned short* __restrict__ W,
              float* __restrict__ C) {
  gemm_body<true>(A, W, nullptr, C);
}

// ---------------------------------------------------------------------------
// Flash attention (causal).  Q/K/V in [B*S, D] bf16, head slice stride DKn.
// Block: 128 Q rows of one (b,h); 4 waves x 32 rows.  K-tiles of 64.
// ---------------------------------------------------------------------------
__global__ __launch_bounds__(256)
void attn_fwd(const unsigned short* __restrict__ Qg,
              const unsigned short* __restrict__ Kg,
              const unsigned short* __restrict__ Vg,
              unsigned short* __restrict__ Og) {
  const int qt  = blockIdx.x;        // 0..15
  const int bh  = blockIdx.y;        // 0..31
  const int bb  = bh >> 4;
  const int hh  = bh & 15;
  const int tid = threadIdx.x, wid = tid >> 6, lane = tid & 63;
  const int l15 = lane & 15, lg = lane >> 4;
  const int q0  = qt * 128;
  const int wq  = wid * 32;
  const size_t base = (size_t)bb * Sn * Dn + (size_t)hh * DKn;

  __shared__ unsigned short Ks[64 * 64];      // K tile  [key][d]
  __shared__ unsigned short Vt[64 * 72];      // V^T     [d][key], pad to 72
  __shared__ unsigned short Ps[4][32 * 72];   // per-wave P, pad to 72

  // Q fragments (A-operand layout: row = l15, k = lg*8 + r)
  bf16x8 qf[2][2];
#pragma unroll
  for (int qm = 0; qm < 2; ++qm)
#pragma unroll
    for (int kk = 0; kk < 2; ++kk)
      qf[qm][kk] = *(const bf16x8*)(Qg + base +
                   (size_t)(q0 + wq + qm * 16 + l15) * Dn + kk * 32 + lg * 8);

  f32x4 oacc[2][4] = {};
  float mrun[2][4], lrun[2][4];
#pragma unroll
  for (int qm = 0; qm < 2; ++qm)
#pragma unroll
    for (int j = 0; j < 4; ++j) { mrun[qm][j] = -1e30f; lrun[qm][j] = 0.f; }

  const float scale = 0.125f;               // 1/sqrt(64)
  const int ktmax   = (q0 + 127) >> 6;      // inclusive
  const int myrowhi = q0 + wq + 31;

  for (int kt = 0; kt <= ktmax; ++kt) {
    const int k0 = kt << 6;

    // stage K tile (linear, global_load_lds)
#pragma unroll
    for (int p = 0; p < 2; ++p) {
      int chunk = p * 4 + wid;              // 0..7
      int r = chunk * 8 + (lane >> 3);
      gload_lds16(Kg + base + (size_t)(k0 + r) * Dn + (lane & 7) * 8, &Ks[chunk * 512]);
    }
    // stage V transposed: read [key][d] coalesced, write Vt[d][key]
#pragma unroll
    for (int p = 0; p < 2; ++p) {
      int e = (p * 256 + tid) * 8;
      int r = e >> 6, c = e & 63;
      union { int4 v; unsigned short u[8]; } un;
      un.v = *(const int4*)(Vg + base + (size_t)(k0 + r) * Dn + c);
#pragma unroll
      for (int i = 0; i < 8; ++i) Vt[(c + i) * 72 + r] = un.u[i];
    }
    __syncthreads();

    if (k0 <= myrowhi) {
      // S = Q K^T  (B-operand: B[k][col] = K[col_key][d])
      f32x4 sf[2][4] = {};
#pragma unroll
      for (int kn = 0; kn < 4; ++kn) {
        bf16x8 kf0 = *(const bf16x8*)(&Ks[(kn * 16 + l15) * 64 + lg * 8]);
        bf16x8 kf1 = *(const bf16x8*)(&Ks[(kn * 16 + l15) * 64 + 32 + lg * 8]);
#pragma unroll
        for (int qm = 0; qm < 2; ++qm) {
          sf[qm][kn] = mfma16(qf[qm][0], kf0, sf[qm][kn]);
          sf[qm][kn] = mfma16(qf[qm][1], kf1, sf[qm][kn]);
        }
      }
      const bool needmask = (k0 + 63) > (q0 + wq);
      // scale + causal mask
#pragma unroll
      for (int qm = 0; qm < 2; ++qm)
#pragma unroll
        for (int kn = 0; kn < 4; ++kn)
#pragma unroll
          for (int j = 0; j < 4; ++j) {
            float v = sf[qm][kn][j] * scale;
            if (needmask) {
              int rg = q0 + wq + qm * 16 + lg * 4 + j;
              int cg = k0 + kn * 16 + l15;
              if (cg > rg) v = -1e30f;
            }
            sf[qm][kn][j] = v;
          }
      // row max (16-lane groups hold one row's 16 cols per kn frag)
      float pm[2][4];
#pragma unroll
      for (int qm = 0; qm < 2; ++qm)
#pragma unroll
        for (int j = 0; j < 4; ++j) {
          float t = fmaxf(fmaxf(sf[qm][0][j], sf[qm][1][j]),
                          fmaxf(sf[qm][2][j], sf[qm][3][j]));
          t = fmaxf(t, __shfl_xor(t, 1, 16));
          t = fmaxf(t, __shfl_xor(t, 2, 16));
          t = fmaxf(t, __shfl_xor(t, 4, 16));
          t = fmaxf(t, __shfl_xor(t, 8, 16));
          pm[qm][j] = t;
        }
      // online-softmax update
#pragma unroll
      for (int qm = 0; qm < 2; ++qm)
#pragma unroll
        for (int j = 0; j < 4; ++j) {
          float mnew = fmaxf(mrun[qm][j], pm[qm][j]);
          float corr = __expf(mrun[qm][j] - mnew);
          mrun[qm][j] = mnew;
          lrun[qm][j] *= corr;
#pragma unroll
          for (int dn = 0; dn < 4; ++dn) oacc[qm][dn][j] *= corr;
        }
      // P = exp(S - m), row sums
      float rs[2][4] = {};
#pragma unroll
      for (int qm = 0; qm < 2; ++qm)
#pragma unroll
        for (int kn = 0; kn < 4; ++kn)
#pragma unroll
          for (int j = 0; j < 4; ++j) {
            float p = __expf(sf[qm][kn][j] - mrun[qm][j]);
            sf[qm][kn][j] = p;
            rs[qm][j] += p;
          }
#pragma unroll
      for (int qm = 0; qm < 2; ++qm)
#pragma unroll
        for (int j = 0; j < 4; ++j) {
          float t = rs[qm][j];
          t += __shfl_xor(t, 1, 16);
          t += __shfl_xor(t, 2, 16);
          t += __shfl_xor(t, 4, 16);
          t += __shfl_xor(t, 8, 16);
          lrun[qm][j] += t;
        }
      // P (C-layout) -> LDS -> A-layout for PV
#pragma unroll
      for (int qm = 0; qm < 2; ++qm)
#pragma unroll
        for (int kn = 0; kn < 4; ++kn)
#pragma unroll
          for (int j = 0; j < 4; ++j)
            Ps[wid][(qm * 16 + lg * 4 + j) * 72 + kn * 16 + l15] = f2bf(sf[qm][kn][j]);
      // O += P V
#pragma unroll
      for (int kk = 0; kk < 2; ++kk) {
        bf16x8 pf[2];
#pragma unroll
        for (int qm = 0; qm < 2; ++qm)
          pf[qm] = *(const bf16x8*)(&Ps[wid][(qm * 16 + l15) * 72 + kk * 32 + lg * 8]);
#pragma unroll
        for (int dn = 0; dn < 4; ++dn) {
          bf16x8 vf = *(const bf16x8*)(&Vt[(dn * 16 + l15) * 72 + kk * 32 + lg * 8]);
#pragma unroll
          for (int qm = 0; qm < 2; ++qm)
            oacc[qm][dn] = mfma16(pf[qm], vf, oacc[qm][dn]);
        }
      }
    }
    __syncthreads();
  }

  // epilogue: O /= l, write bf16
#pragma unroll
  for (int qm = 0; qm < 2; ++qm)
#pragma unroll
    for (int dn = 0; dn < 4; ++dn)
#pragma unroll
      for (int j = 0; j < 4; ++j) {
        float v = oacc[qm][dn][j] / lrun[qm][j];
        int row = q0 + wq + qm * 16 + lg * 4 + j;
        Og[base + (size_t)row * Dn + dn * 16 + l15] = f2bf(v);
      }
}

// ---------------------------------------------------------------------------
extern "C" void kernel_launch(void* const* d_in, const int* in_sizes, int n_in,
                              void* d_out, int out_size, void* d_ws, size_t ws_size,
                              hipStream_t stream) {
  const float* x  = (const float*)d_in[0];
  const float* Wq = (const float*)d_in[1];
  const float* Wk = (const float*)d_in[2];
  const float* Wv = (const float*)d_in[3];
  const float* Wo = (const float*)d_in[4];
  float* out = (float*)d_out;

  char* ws = (char*)d_ws;
  size_t off = 0;
  unsigned short* xb  = (unsigned short*)(ws + off); off += (size_t)Mrows * Dn * 2;
  unsigned short* wqb = (unsigned short*)(ws + off); off += (size_t)Dn * Dn * 2;
  unsigned short* wkb = (unsigned short*)(ws + off); off += (size_t)Dn * Dn * 2;
  unsigned short* wvb = (unsigned short*)(ws + off); off += (size_t)Dn * Dn * 2;
  unsigned short* wob = (unsigned short*)(ws + off); off += (size_t)Dn * Dn * 2;
  unsigned short* Qb  = (unsigned short*)(ws + off); off += (size_t)Mrows * Dn * 2;
  unsigned short* Kb  = (unsigned short*)(ws + off); off += (size_t)Mrows * Dn * 2;
  unsigned short* Vb  = (unsigned short*)(ws + off); off += (size_t)Mrows * Dn * 2;
  unsigned short* Ob  = (unsigned short*)(ws + off); off += (size_t)Mrows * Dn * 2;

  const int nx = Mrows * Dn;       // 4194304
  const int nw = Dn * Dn;          // 1048576
  cvt_f32_bf16<<<nx / 4 / 256, 256, 0, stream>>>(x,  xb,  nx);
  cvt_f32_bf16<<<nw / 4 / 256, 256, 0, stream>>>(Wq, wqb, nw);
  cvt_f32_bf16<<<nw / 4 / 256, 256, 0, stream>>>(Wk, wkb, nw);
  cvt_f32_bf16<<<nw / 4 / 256, 256, 0, stream>>>(Wv, wvb, nw);
  cvt_f32_bf16<<<nw / 4 / 256, 256, 0, stream>>>(Wo, wob, nw);

  gemm_qkv<<<dim3(Mrows / 128, Dn / 128, 3), 256, 0, stream>>>(xb, wqb, wkb, wvb, Qb, Kb, Vb);
  attn_fwd<<<dim3(Sn / 128, Bn * Hn), 256, 0, stream>>>(Qb, Kb, Vb, Ob);
  gemm_out<<<dim3(Mrows / 128, Dn / 128), 256, 0, stream>>>(Ob, wob, out);
}